// Round 10
// baseline (211.360 us; speedup 1.0000x reference)
//
#include <hip/hip_runtime.h>
#include <hip/hip_bf16.h>
#include <math.h>

// Problem: B=2, S=2048, D=1024, H=16, dk=64. fp32 in/out, bf16 MFMA compute.
#define NUM_HEADS 16
#define DK 64
#define SEQ 2048
#define BATCHN 2
#define DM 1024
#define BS (BATCHN*SEQ)          // 4096
#define LSCALE 0.18033688011112042f   // 0.125 * log2(e), folded into Q

typedef __bf16 bf16x8 __attribute__((ext_vector_type(8)));
typedef float floatx4 __attribute__((ext_vector_type(4)));
typedef unsigned short ushort;
typedef unsigned int uint;

__device__ __forceinline__ ushort f2bu(float f){
    union { __hip_bfloat16 h; ushort u; } cv; cv.h = __float2bfloat16(f); return cv.u;
}
__device__ __forceinline__ uint packbf(float a, float b){
    return (uint)f2bu(a) | ((uint)f2bu(b) << 16);
}
__device__ __forceinline__ float bu2f(ushort u){
    union { uint u; float f; } cv; cv.u = (uint)u << 16; return cv.f;
}
// async global->LDS, 16 B per lane; LDS dst must be wave-uniform-base + lane*16
__device__ __forceinline__ void gl16(const void* g, void* l){
    __builtin_amdgcn_global_load_lds(
        (const __attribute__((address_space(1))) unsigned int*)g,
        (__attribute__((address_space(3))) unsigned int*)l, 16, 0, 0);
}

// ---------------------------------------------------------------------------
// Fused fp32->bf16 casts + RoPE table (one launch, 4352 blocks).
// ---------------------------------------------------------------------------
__global__ __launch_bounds__(256)
void castall(const float* __restrict__ x,  const float* __restrict__ wq,
             const float* __restrict__ wk, const float* __restrict__ wv,
             const float* __restrict__ wo, const int* __restrict__ pos,
             ushort* __restrict__ xb, ushort* __restrict__ wqkb,
             ushort* __restrict__ wvb, ushort* __restrict__ wob,
             float2* __restrict__ tab)
{
    int bid = blockIdx.x;
    if (bid >= 4096) {
        int idx = (bid - 4096)*256 + threadIdx.x;   // 0..65535
        int s = idx >> 5, i = idx & 31;
        float invf = expf(-0.28782313662425575f * (float)i);  // ln(1e4)/32
        float ang = (float)pos[s] * invf;
        float sn, cs; sincosf(ang, &sn, &cs);
        tab[idx] = make_float2(cs, sn);
        return;
    }
    const float* src; ushort* dst; int off;
    if (bid < 2048)      { src = x;  dst = xb;             off = bid; }
    else if (bid < 2560) { src = wq; dst = wqkb;           off = bid - 2048; }
    else if (bid < 3072) { src = wk; dst = wqkb + 1048576; off = bid - 2560; }
    else if (bid < 3584) { src = wv; dst = wvb;            off = bid - 3072; }
    else                 { src = wo; dst = wob;            off = bid - 3584; }
    int i = off*2048 + threadIdx.x*8;
    float4 a = *(const float4*)(src+i);
    float4 b = *(const float4*)(src+i+4);
    uint4 o;
    o.x = packbf(a.x, a.y);
    o.y = packbf(a.z, a.w);
    o.z = packbf(b.x, b.y);
    o.w = packbf(b.z, b.w);
    *(uint4*)(dst+i) = o;
}

// ---------------------------------------------------------------------------
// Fused projections, 128x128 tiles (768 blocks), global_load_lds staging with
// LDS DOUBLE-BUFFER: one barrier/iter; prefetch of tile k+1 issued right
// after the barrier, overlapping its L2 latency with tile k's compute. The
// compiler's per-wave `s_waitcnt vmcnt(0)` before s_barrier is what makes the
// prefetched data visible at the next iteration's top barrier.
//   blocks 0..511  : QK proj + RoPE scatter [b,h,s,64]; Q scaled by LSCALE.
//   blocks 512..767: V^T proj row-major [1024, 4096].
// ---------------------------------------------------------------------------
__global__ __launch_bounds__(256)
void proj_fused(const ushort* __restrict__ xb, const ushort* __restrict__ Wqkb,
                const ushort* __restrict__ Wvb, ushort* __restrict__ Qb,
                ushort* __restrict__ VTp, const float2* __restrict__ rope)
{
    __shared__ ushort As[2][128][32];
    __shared__ ushort Bs[2][128][32];

    const int bid = blockIdx.x;
    const ushort* A; const ushort* W; int row0, col0, mode;
    if (bid < 512) { A = xb;  W = Wqkb; row0 = (bid >> 4) * 128;
                     col0 = (bid & 15) * 128;  mode = 1; }
    else           { int i = bid - 512; A = Wvb; W = xb;
                     row0 = (i >> 5) * 128; col0 = (i & 31) * 128; mode = 2; }

    const int t = threadIdx.x;
    const int w = t >> 6;
    const int L = t & 63;
    const int lr = L & 15;
    const int lq = L >> 4;
    const int wrow = w * 32;

    floatx4 acc[2][8];
    #pragma unroll
    for (int i = 0; i < 2; ++i)
        #pragma unroll
        for (int j = 0; j < 8; ++j)
            acc[i][j] = (floatx4){0.f,0.f,0.f,0.f};

    const int rr = t >> 2, ko = (t & 3) * 8;   // LDS offset = t*16 B (lane-contig)
    const ushort* ga = A + (size_t)(row0 + rr) * DM + ko;
    const ushort* gb = W + (size_t)(col0 + rr) * DM + ko;

    // preload tile 0 into buffer 0
    gl16(ga,                   &As[0][rr][ko]);
    gl16(ga + (size_t)64*DM,   &As[0][rr + 64][ko]);
    gl16(gb,                   &Bs[0][rr][ko]);
    gl16(gb + (size_t)64*DM,   &Bs[0][rr + 64][ko]);

    for (int k0 = 0; k0 < DM; k0 += 32) {
        const int cur = (k0 >> 5) & 1;
        __syncthreads();   // drains own vmcnt: buf cur ready; buf cur^1 free
        if (k0 + 32 < DM) {
            const ushort* ga2 = ga + k0 + 32;
            const ushort* gb2 = gb + k0 + 32;
            gl16(ga2,                   &As[cur^1][rr][ko]);
            gl16(ga2 + (size_t)64*DM,   &As[cur^1][rr + 64][ko]);
            gl16(gb2,                   &Bs[cur^1][rr][ko]);
            gl16(gb2 + (size_t)64*DM,   &Bs[cur^1][rr + 64][ko]);
        }

        bf16x8 aF0 = *(const bf16x8*)&As[cur][wrow + lr][lq*8];
        bf16x8 aF1 = *(const bf16x8*)&As[cur][wrow + 16 + lr][lq*8];
        #pragma unroll
        for (int tc = 0; tc < 8; ++tc) {
            bf16x8 bF = *(const bf16x8*)&Bs[cur][tc*16 + lr][lq*8];
            acc[0][tc] = __builtin_amdgcn_mfma_f32_16x16x32_bf16(aF0, bF, acc[0][tc], 0, 0, 0);
            acc[1][tc] = __builtin_amdgcn_mfma_f32_16x16x32_bf16(aF1, bF, acc[1][tc], 0, 0, 0);
        }
    }

    // C layout: col = col0 + tc*16 + lr, row = row0+wrow+tr*16+lq*4+r
    if (mode == 2) {
        #pragma unroll
        for (int tr = 0; tr < 2; ++tr)
            #pragma unroll
            for (int tc = 0; tc < 8; ++tc)
                #pragma unroll
                for (int r = 0; r < 4; ++r) {
                    int m = row0 + wrow + tr*16 + lq*4 + r;
                    int c = col0 + tc*16 + lr;
                    VTp[(size_t)m * BS + c] = f2bu(acc[tr][tc][r]);
                }
    } else {
        const int mat = col0 >> 10;             // 0 = Q, 1 = K (tile never straddles)
        const int base_hh = (col0 & 1023) >> 6;
        ushort* out = Qb + (size_t)mat * (BATCHN*NUM_HEADS*SEQ*DK);
        const float qscale = mat ? 1.f : LSCALE;
        #pragma unroll
        for (int tr = 0; tr < 2; ++tr)
            #pragma unroll
            for (int tc = 0; tc < 8; ++tc)
                #pragma unroll
                for (int r = 0; r < 4; ++r) {
                    int m = row0 + wrow + tr*16 + lq*4 + r;
                    int b = m >> 11;
                    int s = m & (SEQ - 1);
                    int dd = (tc*16 + lr) & 63;
                    int hh = base_hh + (tc >> 2);
                    float v = acc[tr][tc][r];
                    float o = __shfl_xor(v, 1, 64);
                    float2 cs = rope[s*32 + (dd >> 1)];
                    float rv = (dd & 1) ? fmaf(o, cs.y,  v * cs.x)
                                        : fmaf(-o, cs.y, v * cs.x);
                    out[((size_t)((b*NUM_HEADS + hh)*SEQ + s))*DK + dd] =
                        f2bu(rv * qscale);
                }
    }
}

// ---------------------------------------------------------------------------
// Out projection, 128x64 tiles (512 blocks = 2/CU), double-buffered
// global_load_lds staging. out[m,n] = sum_k attnb[m,k]*Wo[n,k], fp32.
// ---------------------------------------------------------------------------
__global__ __launch_bounds__(256)
void gemm_out(const ushort* __restrict__ A, const ushort* __restrict__ W,
              float* __restrict__ out)
{
    __shared__ ushort As[2][128][32];
    __shared__ ushort Bs[2][64][32];

    const int t = threadIdx.x;
    const int w = t >> 6;
    const int L = t & 63;
    const int lr = L & 15;
    const int lq = L >> 4;
    const int row0 = blockIdx.y * 128;
    const int col0 = blockIdx.x * 64;
    const int wrow = w * 32;

    floatx4 acc[2][4];
    #pragma unroll
    for (int i = 0; i < 2; ++i)
        #pragma unroll
        for (int j = 0; j < 4; ++j)
            acc[i][j] = (floatx4){0.f,0.f,0.f,0.f};

    const int rr = t >> 2, ko = (t & 3) * 8;
    const ushort* ga = A + (size_t)(row0 + rr) * DM + ko;
    const ushort* gb = W + (size_t)(col0 + rr) * DM + ko;

    gl16(ga,                   &As[0][rr][ko]);
    gl16(ga + (size_t)64*DM,   &As[0][rr + 64][ko]);
    gl16(gb,                   &Bs[0][rr][ko]);

    for (int k0 = 0; k0 < DM; k0 += 32) {
        const int cur = (k0 >> 5) & 1;
        __syncthreads();
        if (k0 + 32 < DM) {
            const ushort* ga2 = ga + k0 + 32;
            const ushort* gb2 = gb + k0 + 32;
            gl16(ga2,                   &As[cur^1][rr][ko]);
            gl16(ga2 + (size_t)64*DM,   &As[cur^1][rr + 64][ko]);
            gl16(gb2,                   &Bs[cur^1][rr][ko]);
        }

        bf16x8 aF0 = *(const bf16x8*)&As[cur][wrow + lr][lq*8];
        bf16x8 aF1 = *(const bf16x8*)&As[cur][wrow + 16 + lr][lq*8];
        #pragma unroll
        for (int tc = 0; tc < 4; ++tc) {
            bf16x8 bF = *(const bf16x8*)&Bs[cur][tc*16 + lr][lq*8];
            acc[0][tc] = __builtin_amdgcn_mfma_f32_16x16x32_bf16(aF0, bF, acc[0][tc], 0, 0, 0);
            acc[1][tc] = __builtin_amdgcn_mfma_f32_16x16x32_bf16(aF1, bF, acc[1][tc], 0, 0, 0);
        }
    }

    #pragma unroll
    for (int tr = 0; tr < 2; ++tr)
        #pragma unroll
        for (int tc = 0; tc < 4; ++tc)
            #pragma unroll
            for (int r = 0; r < 4; ++r) {
                int m = row0 + wrow + tr*16 + lq*4 + r;
                int c = col0 + tc*16 + lr;
                out[(size_t)m * DM + c] = acc[tr][tc][r];
            }
}

// ---------------------------------------------------------------------------
// Flash attention, bf16 MFMA, no-max softmax, transposed QK (S^T = K·Q^T).
// Work split into near-uniform chunks of <=8 key-tiles: nch(qt) = qt/8+1.
// grid.x = 80 per (h,b) -> 2560 blocks. qt<8: direct write. qt>=8: bf16
// O-partial + fp32 l per chunk; combine() reduces.   (unchanged from r9)
// ---------------------------------------------------------------------------
__global__ __launch_bounds__(256)
void attn_mfma(const ushort* __restrict__ Qb, const ushort* __restrict__ Kb,
               const ushort* __restrict__ VT, ushort* __restrict__ attnb,
               ushort* __restrict__ Opart, float* __restrict__ lpart)
{
    __shared__ ushort Ks[64][72];      // [key][dim]
    __shared__ ushort Vs[64][72];      // [dim][key]
    __shared__ ushort Ps[4][16][72];   // per-wave P[q][key]

    const int t = threadIdx.x;
    const int w = t >> 6;
    const int L = t & 63;
    const int lr = L & 15, lq = L >> 4;
    const int h  = blockIdx.y;
    const int b  = blockIdx.z;

    // chunk mapping: bx 0..79
    int qt, chunk, nch;
    {
        const int bx = blockIdx.x;
        if (bx < 8)       { qt = bx;              chunk = 0;     nch = 1; }
        else if (bx < 24) { int i = bx - 8;  qt = 8  + (i>>1); chunk = i&1;        nch = 2; }
        else if (bx < 48) { int i = bx - 24; int q3 = i/3; qt = 16 + q3; chunk = i - q3*3; nch = 3; }
        else              { int i = bx - 48; qt = 24 + (i>>2); chunk = i&3;        nch = 4; }
    }
    const int nt = qt + 1;
    const int t0 = (nt * chunk) / nch;
    const int t1 = (nt * (chunk + 1)) / nch;
    const int q0 = qt * 64;
    const int qw = q0 + w * 16;
    const size_t qkbase = (size_t)(b*NUM_HEADS + h) * SEQ * DK;

    bf16x8 qF0, qF1;
    {
        const ushort* qp = Qb + qkbase + (size_t)(qw + lr) * DK + lq*8;
        qF0 = *(const bf16x8*)qp;
        qF1 = *(const bf16x8*)(qp + 32);
    }

    floatx4 O[4];
    #pragma unroll
    for (int g = 0; g < 4; ++g) O[g] = (floatx4){0.f,0.f,0.f,0.f};
    float l_lane = 0.f;

    const int sr = t >> 3, sc = (t & 7) * 8;
    const ushort* kp0 = Kb + qkbase + (size_t)sr * DK + sc;
    const ushort* vp0 = VT + ((size_t)(h*DK + sr)) * BS + b*SEQ + sc;

    for (int tile = t0; tile < t1; ++tile) {
        const int kb = tile * 64;
        __syncthreads();
        {
            uint4 k0v = *(const uint4*)(kp0 + (size_t)kb * DK);
            uint4 k1v = *(const uint4*)(kp0 + (size_t)(kb + 32) * DK);
            uint4 v0v = *(const uint4*)(vp0 + kb);
            uint4 v1v = *(const uint4*)(vp0 + (size_t)32 * BS + kb);
            *(uint4*)&Ks[sr][sc]      = k0v;
            *(uint4*)&Ks[sr + 32][sc] = k1v;
            *(uint4*)&Vs[sr][sc]      = v0v;
            *(uint4*)&Vs[sr + 32][sc] = v1v;
        }
        __syncthreads();

        const bool lastt = (tile == nt - 1);
        const int lim = qw + lr - kb;          // key offset <= lim is unmasked

        #pragma unroll
        for (int g = 0; g < 4; ++g) {
            floatx4 s = (floatx4){0.f,0.f,0.f,0.f};
            bf16x8 kf0 = *(const bf16x8*)&Ks[g*16 + lr][lq*8];
            bf16x8 kf1 = *(const bf16x8*)&Ks[g*16 + lr][32 + lq*8];
            // S^T = K·Q^T: lane -> q = qw+lr (col), key = kb+g*16+lq*4+r (row)
            s = __builtin_amdgcn_mfma_f32_16x16x32_bf16(kf0, qF0, s, 0, 0, 0);
            s = __builtin_amdgcn_mfma_f32_16x16x32_bf16(kf1, qF1, s, 0, 0, 0);
            float p0, p1, p2, p3;
            if (lastt) {
                const int kbase = g*16 + lq*4;
                p0 = (kbase + 0 <= lim) ? exp2f(s[0]) : 0.f;
                p1 = (kbase + 1 <= lim) ? exp2f(s[1]) : 0.f;
                p2 = (kbase + 2 <= lim) ? exp2f(s[2]) : 0.f;
                p3 = (kbase + 3 <= lim) ? exp2f(s[3]) : 0.f;
            } else {
                p0 = exp2f(s[0]); p1 = exp2f(s[1]);
                p2 = exp2f(s[2]); p3 = exp2f(s[3]);
            }
            l_lane += (p0 + p1) + (p2 + p3);
            uint2 pk;
            pk.x = packbf(p0, p1);
            pk.y = packbf(p2, p3);
            *(uint2*)&Ps[w][lr][g*16 + lq*4] = pk;
        }
        asm volatile("s_waitcnt lgkmcnt(0)" ::: "memory");

        #pragma unroll
        for (int c = 0; c < 2; ++c) {
            bf16x8 pF = *(const bf16x8*)&Ps[w][lr][c*32 + lq*8];
            #pragma unroll
            for (int g2 = 0; g2 < 4; ++g2) {
                bf16x8 vf = *(const bf16x8*)&Vs[g2*16 + lr][c*32 + lq*8];
                O[g2] = __builtin_amdgcn_mfma_f32_16x16x32_bf16(pF, vf, O[g2], 0, 0, 0);
            }
        }
    }

    // l for q=qw+lr: sum across the 4 lq lanes sharing lr
    l_lane += __shfl_xor(l_lane, 16, 64);
    l_lane += __shfl_xor(l_lane, 32, 64);

    if (nch == 1) {
        #pragma unroll
        for (int r = 0; r < 4; ++r) {
            float lv = __shfl(l_lane, lq*4 + r, 64);   // l for q row lq*4+r
            float li = 1.f / lv;
            int s = qw + lq*4 + r;
            #pragma unroll
            for (int g2 = 0; g2 < 4; ++g2)
                attnb[((size_t)(b*SEQ + s))*DM + h*DK + g2*16 + lr] = f2bu(O[g2][r] * li);
        }
    } else {
        const int slot = ((b*NUM_HEADS + h)*24 + (qt - 8))*4 + chunk;
        ushort* Op = Opart + (size_t)slot * 4096;
        #pragma unroll
        for (int r = 0; r < 4; ++r) {
            int ql = w*16 + lq*4 + r;
            #pragma unroll
            for (int g2 = 0; g2 < 4; ++g2)
                Op[ql*64 + g2*16 + lr] = f2bu(O[g2][r]);
        }
        if (lq == 0) lpart[(size_t)slot*64 + w*16 + lr] = l_lane;
    }
}

// ---------------------------------------------------------------------------
// Combine: for qt>=8, O = (sum_c O_c)/(sum_c l_c) -> attnb bf16.
// grid 768 = 32 (b,h) x 24 qt.
// ---------------------------------------------------------------------------
__global__ __launch_bounds__(256)
void combine(const ushort* __restrict__ Opart, const float* __restrict__ lpart,
             ushort* __restrict__ attnb)
{
    int gx = blockIdx.x;
    int qti = gx % 24, bh = gx / 24;
    int h = bh & 15, b = bh >> 4;
    int qt = 8 + qti;
    int nch = (qt >> 3) + 1;          // 2..4
    int tid = threadIdx.x;
    int row = tid >> 2, c0 = (tid & 3) * 16;
    const int base_slot = (bh*24 + qti)*4;

    float acc[16];
    #pragma unroll
    for (int e = 0; e < 16; ++e) acc[e] = 0.f;
    float l = 0.f;

    for (int c = 0; c < nch; ++c) {
        const ushort* Op = Opart + (size_t)(base_slot + c)*4096 + row*64 + c0;
        uint4 u0 = *(const uint4*)(Op);
        uint4 u1 = *(const uint4*)(Op + 8);
        const ushort* h0 = (const ushort*)&u0;
        const ushort* h1 = (const ushort*)&u1;
        #pragma unroll
        for (int e = 0; e < 8; ++e) { acc[e]   += bu2f(h0[e]); }
        #pragma unroll
        for (int e = 0; e < 8; ++e) { acc[8+e] += bu2f(h1[e]); }
        l += lpart[(size_t)(base_slot + c)*64 + row];
    }
    float li = 1.f / l;
    int s = qt*64 + row;
    ushort* dst = attnb + ((size_t)(b*SEQ + s))*DM + h*DK + c0;
    #pragma unroll
    for (int e = 0; e < 16; ++e) dst[e] = f2bu(acc[e] * li);
}

// ---------------------------------------------------------------------------
extern "C" void kernel_launch(void* const* d_in, const int* in_sizes, int n_in,
                              void* d_out, int out_size, void* d_ws, size_t ws_size,
                              hipStream_t stream) {
    const float* x   = (const float*)d_in[0];
    const float* Wq  = (const float*)d_in[1];
    const float* Wk  = (const float*)d_in[2];
    const float* Wv  = (const float*)d_in[3];
    const float* Wo  = (const float*)d_in[4];
    const int*   pos = (const int*)d_in[5];
    float* out = (float*)d_out;

    const size_t MB = 1u << 20;
    char* ws = (char*)d_ws;
    // xb/Wqkb/Wvb dead after projections; Opart (24 MB) aliases them.
    ushort* xb    = (ushort*)(ws);             //  8 MB  [4096,1024]
    ushort* Wqkb  = (ushort*)(ws +  8*MB);     //  4 MB  [Wq;Wk]
    ushort* Wvb   = (ushort*)(ws + 12*MB);     //  2 MB
    ushort* Opart = (ushort*)(ws);             // 24 MB  [3072 slots][64][64] bf16
    float*  lpart = (float*)(ws + 24*MB);      //  768 KB
    ushort* Qb    = (ushort*)(ws + 25*MB);     //  8 MB  [b,h,s,64] (Q scaled)
    ushort* Kb    = (ushort*)(ws + 33*MB);     //  8 MB  (== Qb + 4194304)
    ushort* VT    = (ushort*)(ws + 41*MB);     //  8 MB  [h*64+dv, b*2048+s]
    ushort* attnb = (ushort*)(ws + 49*MB);     //  8 MB  [4096,1024]
    float2* ropeT = (float2*)(ws + 57*MB);     //  0.5 MB
    ushort* Wob   = (ushort*)(ws + 58*MB);     //  2 MB  (survives to out-GEMM)

    dim3 blk(256);
    castall<<<4352, blk, 0, stream>>>(x, Wq, Wk, Wv, Wo, pos,
                                      xb, Wqkb, Wvb, Wob, ropeT);

    proj_fused<<<768, blk, 0, stream>>>(xb, Wqkb, Wvb, Qb, VT, ropeT);

    attn_mfma<<<dim3(80, NUM_HEADS, BATCHN), blk, 0, stream>>>(Qb, Kb, VT, attnb,
                                                               Opart, lpart);
    combine<<<768, blk, 0, stream>>>(Opart, lpart, attnb);

    gemm_out<<<dim3(16,32), blk, 0, stream>>>(attnb, Wob, out);
}